// Round 4
// baseline (322.257 us; speedup 1.0000x reference)
//
#include <hip/hip_runtime.h>
#include <hip/hip_bf16.h>
#include <cstdint>
#include <cstddef>

#define EMB_K   1024
#define EMB_C   256
#define HWB     4096        // 64*64 per batch
#define NPIX    65536       // 16*4096

typedef __bf16 bf16x8 __attribute__((ext_vector_type(8)));
typedef float  f32x4  __attribute__((ext_vector_type(4)));
// 4-byte-aligned variant for the out+1 (4 mod 16) store path
typedef float  f32x4a __attribute__((ext_vector_type(4), aligned(4)));

__device__ __forceinline__ unsigned short bf16bits(float v) {
  __hip_bfloat16 h = __float2bfloat16(v);
  return __builtin_bit_cast(unsigned short, h);
}

// ---- emb -> bf16 + fp32 norms; zero loss + ctr ----
__global__ void k_emb(const float* __restrict__ emb, unsigned short* __restrict__ emb_bf,
                      float* __restrict__ enorm, float* __restrict__ loss,
                      unsigned* __restrict__ ctr) {
  int k = blockIdx.x;      // 0..1023
  int c = threadIdx.x;     // 0..255
  if (k == 0 && c == 0) { *loss = 0.f; *ctr = 0u; }
  float v = emb[(size_t)k * EMB_C + c];
  emb_bf[(size_t)k * EMB_C + c] = bf16bits(v);
  float s = v * v;
  for (int m = 32; m; m >>= 1) s += __shfl_down(s, m, 64);
  __shared__ float red[4];
  int lane = c & 63, w = c >> 6;
  if (lane == 0) red[w] = s;
  __syncthreads();
  if (c == 0) enorm[k] = red[0] + red[1] + red[2] + red[3];
}

// ---- K1: x[b][c][hw] -> A[n][c] bf16 (row-major, 512B rows) + xn f32 ----
__global__ __launch_bounds__(256) void
k_tr(const float* __restrict__ x, unsigned short* __restrict__ A,
     float* __restrict__ xn_g) {
  __shared__ unsigned char tile[64 * 512];   // 32 KB
  __shared__ float xn_l[64];
  int t  = threadIdx.x;
  int n0 = blockIdx.x * 64;
  int b  = n0 >> 12, hw0 = n0 & 4095;
  int nl = t & 63, qq = t >> 6;              // qq = c-quarter 0..3
  if (t < 64) xn_l[t] = 0.f;
  __syncthreads();
  const float* xp = x + (size_t)b * (EMB_C * HWB) + hw0 + nl;
  float xn = 0.f;
#pragma unroll
  for (int o = 0; o < 8; ++o) {
    int cc = qq * 8 + o;                     // c-chunk 0..31 (8 c each)
    float v[8];
#pragma unroll
    for (int j = 0; j < 8; ++j) {
      v[j] = xp[(size_t)(cc * 8 + j) * HWB]; // 256B-coalesced per instr
      xn += v[j] * v[j];
    }
    union { unsigned u[4]; uint4 q; } pk;
#pragma unroll
    for (int m = 0; m < 4; ++m)
      pk.u[m] = (unsigned)bf16bits(v[2 * m]) | ((unsigned)bf16bits(v[2 * m + 1]) << 16);
    int pos = ((cc >> 3) << 3) | ((cc & 7) ^ (nl & 7));
    *(uint4*)(tile + nl * 512 + pos * 16) = pk.q;
  }
  atomicAdd(&xn_l[nl], xn);                  // 4 partials per n
  __syncthreads();
  if (t < 64) xn_g[n0 + t] = xn_l[t];
  uint4* Adst = (uint4*)A + (size_t)n0 * 32; // 32 x 16B chunks per row
#pragma unroll
  for (int k = 0; k < 8; ++k) {
    int id = k * 256 + t;                    // chunk 0..2047 (64 rows x 32)
    int n = id >> 5, slot = id & 31;
    int pos = ((slot >> 3) << 3) | ((slot & 7) ^ (n & 7));
    Adst[id] = *(const uint4*)(tile + n * 512 + pos * 16);  // 1KB/wave stores
  }
}

// ---- K2: GEMM + argmin + loss. 512 blocks x 512 thr. ----
// Barrier-free reg-streamed k-loop: the GEMM contraction (C=256) is entirely
// in af[4][8] registers, so k-tiles carry NO accumulation -> no shared B
// buffer needed. Each lane loads its B fragment directly from embbf (16B
// global loads, L1/L2-resident 512KB matrix); compiler pipelines loads under
// MFMA with counted vmcnt. Zero barriers / zero LDS traffic in the loop —
// escapes the 2-phase stage+vmcnt+barrier ceiling (607 TF, R2/R3 measured).
__global__ __launch_bounds__(512, 4) void
k_gemm(const unsigned short* __restrict__ A, const unsigned short* __restrict__ embbf,
       const float* __restrict__ enorm, const float* __restrict__ xn_g,
       unsigned* __restrict__ keys_g, float* __restrict__ out,
       float* __restrict__ loss, unsigned* __restrict__ ctr) {
  __shared__ float    cjl[1024];
  __shared__ unsigned keys_l[128];
  __shared__ float    xn_l[128];
  __shared__ float    red[8];

  int n0 = blockIdx.x * 128;
  int t = threadIdx.x, w = t >> 6, lane = t & 63;
  int quad = lane >> 4, lr = lane & 15;
  int g  = w >> 2;       // n-group 0..1 (64 n)
  int h2 = w & 3;        // k-quarter (16 of each 64-k tile)

  for (int i = t; i < 1024; i += 512) cjl[i] = 0.375f - 0.5f * enorm[i];
  if (t < 128) { keys_l[t] = 0u; xn_l[t] = xn_g[n0 + t]; }

  // ---- A fragments direct from global (one-shot, 64KB/block from L3/L2) ----
  bf16x8 af[4][8];
#pragma unroll
  for (int i = 0; i < 4; ++i) {
    const unsigned short* ar =
        A + (size_t)(n0 + g * 64 + i * 16 + lr) * EMB_C + quad * 8;
#pragma unroll
    for (int s = 0; s < 8; ++s)
      af[i][s] = *(const bf16x8*)(ar + s * 32);   // col = s*32 + quad*8
  }
  __syncthreads();   // cjl / keys_l / xn_l visible

  // ---- K-loop: 16 tiles of 64 emb rows, fully wave-independent ----
  unsigned best[4][4] = {};
  const unsigned short* bbase = embbf + (size_t)(h2 * 16 + lr) * EMB_C + quad * 8;
  for (int kt = 0; kt < 16; ++kt) {
    const unsigned short* br = bbase + (size_t)kt * 64 * EMB_C;
    int k = kt * 64 + h2 * 16 + lr;
    float cj = cjl[k];
    unsigned kp = 1023u - (unsigned)k;
    f32x4 acc[4] = {};
#pragma unroll
    for (int s = 0; s < 8; ++s) {
      bf16x8 bf = *(const bf16x8*)(br + s * 32);  // B[k][s*32+quad*8 ..]
#pragma unroll
      for (int i = 0; i < 4; ++i)
        acc[i] = __builtin_amdgcn_mfma_f32_16x16x32_bf16(af[i][s], bf, acc[i], 0, 0, 0);
    }
    // fold argmin keys: f = dot + 0.375 - 0.5||e||^2 in (0.04,0.71) -> positive
    // float u32-order-correct; low 10 mantissa bits carry (1023-k).
#pragma unroll
    for (int i = 0; i < 4; ++i)
#pragma unroll
      for (int r = 0; r < 4; ++r) {
        float f = acc[i][r] + cj;
        unsigned key = (__float_as_uint(f) & 0xFFFFFC00u) | kp;
        best[i][r] = best[i][r] > key ? best[i][r] : key;
      }
  }
  __syncthreads();   // k-loop complete before keys_l atomics phase

  // ---- combine keys across k-lanes; k-quarters via LDS atomicMax ----
#pragma unroll
  for (int i = 0; i < 4; ++i)
#pragma unroll
    for (int r = 0; r < 4; ++r) {
      unsigned v = best[i][r];
#pragma unroll
      for (int m = 1; m < 16; m <<= 1) {
        unsigned o = (unsigned)__shfl_xor((int)v, m, 64);
        v = v > o ? v : o;
      }
      if (lr == 0) atomicMax(&keys_l[g * 64 + i * 16 + quad * 4 + r], v);
    }
  __syncthreads();

  // ---- keys export + loss partial: d2 = ||x||^2 + 0.75 - 2*f_hat ----
  if (t < 128) {
    unsigned key = keys_l[t];
    keys_g[n0 + t] = key;
    float fh = __uint_as_float(key & 0xFFFFFC00u);
    float lsum = xn_l[t] + 0.75f - 2.0f * fh;
    for (int m = 32; m; m >>= 1) lsum += __shfl_down(lsum, m, 64);
    if (lane == 0) red[w] = lsum;
  }
  __syncthreads();
  if (t == 0) {
    atomicAdd(loss, red[0] + red[1]);
    __threadfence();
    unsigned done = atomicAdd(ctr, 1u);
    if (done == gridDim.x - 1) {
      float total = atomicAdd(loss, 0.f);   // device-scope read of final sum
      out[0] = 1.0625f * total / 16777216.0f;
    }
  }
}

// ---- K3: gather emb rows -> LDS [64c][256n] -> 1KB/wave contiguous stores ----
__global__ __launch_bounds__(512) void
k_out(const float* __restrict__ emb, const unsigned* __restrict__ keys_g,
      float* __restrict__ out) {
  extern __shared__ float tile[];            // 64 x 256 f32 = 64 KB
  int t  = threadIdx.x;
  int n0 = blockIdx.x * 256;
  int b  = n0 >> 12, hw0 = n0 & 4095;
  int w  = t >> 6, lane = t & 63;
  int n  = t >> 1, ch = t & 1;               // thread pair per n
  int idx = 1023 - (int)(keys_g[n0 + n] & 1023u);
  const float* er = emb + (size_t)idx * EMB_C;
  float* ob = out + 1 + (size_t)b * (EMB_C * HWB) + hw0;
  for (int p = 0; p < 4; ++p) {
    int c0 = p * 64;
    if (p) __syncthreads();
#pragma unroll
    for (int jj = 0; jj < 8; ++jj) {         // 8 x 16B L2-resident gathers
      f32x4 q = *(const f32x4*)(er + c0 + ch * 32 + jj * 4);
#pragma unroll
      for (int m = 0; m < 4; ++m)
        tile[(ch * 32 + jj * 4 + m) * 256 + n] = q[m];
    }
    __syncthreads();
#pragma unroll
    for (int cc = 0; cc < 8; ++cc) {         // wave w: c-rows w*8..w*8+7
      int cl = w * 8 + cc;
      f32x4 q = *(const f32x4*)(tile + cl * 256 + lane * 4);
      *(f32x4a*)(ob + (size_t)(c0 + cl) * HWB + lane * 4) = q;  // 1KB/wave
    }
  }
}

extern "C" void kernel_launch(void* const* d_in, const int* in_sizes, int n_in,
                              void* d_out, int out_size, void* d_ws, size_t ws_size,
                              hipStream_t stream) {
  const float* x   = (const float*)d_in[0];   // [16,256,64,64]
  const float* emb = (const float*)d_in[1];   // [1024,256]
  float* out = (float*)d_out;                 // [1 + 16777216]
  char*  ws  = (char*)d_ws;

  unsigned short* emb_bf = (unsigned short*)ws;                 // 512 KB
  float*          enorm  = (float*)(ws + 524288);               // 4 KB
  float*          loss   = (float*)(ws + 528384);               // 4 B
  unsigned*       ctr    = (unsigned*)(ws + 528388);            // 4 B
  float*          xn_g   = (float*)(ws + 532480);               // 256 KB
  unsigned*       keys_g = (unsigned*)(ws + 794624);            // 256 KB

  // A (bf16 [65536][256], 32 MB) lives inside the out payload, 16B-aligned at
  // out+4 floats. K2 reads it before K3 overwrites out[1..] (stream-ordered).
  unsigned short* A = (unsigned short*)(out + 4);

  hipFuncSetAttribute((const void*)k_out,
                      hipFuncAttributeMaxDynamicSharedMemorySize, 65536);

  k_emb <<<dim3(EMB_K),      dim3(EMB_C), 0,     stream>>>(emb, emb_bf, enorm, loss, ctr);
  k_tr  <<<dim3(NPIX / 64),  dim3(256),   0,     stream>>>(x, A, xn_g);
  k_gemm<<<dim3(NPIX / 128), dim3(512),   0,     stream>>>(A, emb_bf, enorm, xn_g,
                                                           keys_g, out, loss, ctr);
  k_out <<<dim3(NPIX / 256), dim3(512),   65536, stream>>>(emb, keys_g, out);
}

// Round 5
// 227.495 us; speedup vs baseline: 1.4166x; 1.4166x over previous
//
#include <hip/hip_runtime.h>
#include <hip/hip_bf16.h>
#include <cstdint>
#include <cstddef>

#define EMB_K   1024
#define EMB_C   256
#define HWB     4096        // 64*64 per batch
#define NPIX    65536       // 16*4096

typedef __bf16 bf16x8 __attribute__((ext_vector_type(8)));
typedef float  f32x4  __attribute__((ext_vector_type(4)));
// 4-byte-aligned variant for the out+1 (4 mod 16) store path
typedef float  f32x4a __attribute__((ext_vector_type(4), aligned(4)));

__device__ __forceinline__ unsigned short bf16bits(float v) {
  __hip_bfloat16 h = __float2bfloat16(v);
  return __builtin_bit_cast(unsigned short, h);
}

// ---- emb -> bf16 + fp32 norms; zero loss + ctr ----
__global__ void k_emb(const float* __restrict__ emb, unsigned short* __restrict__ emb_bf,
                      float* __restrict__ enorm, float* __restrict__ loss,
                      unsigned* __restrict__ ctr) {
  int k = blockIdx.x;      // 0..1023
  int c = threadIdx.x;     // 0..255
  if (k == 0 && c == 0) { *loss = 0.f; *ctr = 0u; }
  float v = emb[(size_t)k * EMB_C + c];
  emb_bf[(size_t)k * EMB_C + c] = bf16bits(v);
  float s = v * v;
  for (int m = 32; m; m >>= 1) s += __shfl_down(s, m, 64);
  __shared__ float red[4];
  int lane = c & 63, w = c >> 6;
  if (lane == 0) red[w] = s;
  __syncthreads();
  if (c == 0) enorm[k] = red[0] + red[1] + red[2] + red[3];
}

// ---- K1: x[b][c][hw] -> A[n][c] bf16 (row-major, 512B rows) + xn f32 ----
__global__ __launch_bounds__(256) void
k_tr(const float* __restrict__ x, unsigned short* __restrict__ A,
     float* __restrict__ xn_g) {
  __shared__ unsigned char tile[64 * 512];   // 32 KB
  __shared__ float xn_l[64];
  int t  = threadIdx.x;
  int n0 = blockIdx.x * 64;
  int b  = n0 >> 12, hw0 = n0 & 4095;
  int nl = t & 63, qq = t >> 6;              // qq = c-quarter 0..3
  if (t < 64) xn_l[t] = 0.f;
  __syncthreads();
  const float* xp = x + (size_t)b * (EMB_C * HWB) + hw0 + nl;
  float xn = 0.f;
#pragma unroll
  for (int o = 0; o < 8; ++o) {
    int cc = qq * 8 + o;                     // c-chunk 0..31 (8 c each)
    float v[8];
#pragma unroll
    for (int j = 0; j < 8; ++j) {
      v[j] = xp[(size_t)(cc * 8 + j) * HWB]; // 256B-coalesced per instr
      xn += v[j] * v[j];
    }
    union { unsigned u[4]; uint4 q; } pk;
#pragma unroll
    for (int m = 0; m < 4; ++m)
      pk.u[m] = (unsigned)bf16bits(v[2 * m]) | ((unsigned)bf16bits(v[2 * m + 1]) << 16);
    int pos = ((cc >> 3) << 3) | ((cc & 7) ^ (nl & 7));
    *(uint4*)(tile + nl * 512 + pos * 16) = pk.q;
  }
  atomicAdd(&xn_l[nl], xn);                  // 4 partials per n
  __syncthreads();
  if (t < 64) xn_g[n0 + t] = xn_l[t];
  uint4* Adst = (uint4*)A + (size_t)n0 * 32; // 32 x 16B chunks per row
#pragma unroll
  for (int k = 0; k < 8; ++k) {
    int id = k * 256 + t;                    // chunk 0..2047 (64 rows x 32)
    int n = id >> 5, slot = id & 31;
    int pos = ((slot >> 3) << 3) | ((slot & 7) ^ (n & 7));
    Adst[id] = *(const uint4*)(tile + n * 512 + pos * 16);  // 1KB/wave stores
  }
}

// ---- K2: GEMM + argmin + loss. 512 blocks x 512 thr. ----
// Barrier-free reg-streamed k-loop: the GEMM contraction (C=256) is entirely
// in af[4][8] registers, so k-tiles carry NO accumulation -> no shared B
// buffer needed. Each lane loads its B fragment directly from embbf (16B
// global loads, L1/L2-resident 512KB matrix); compiler pipelines loads under
// MFMA with counted vmcnt. Zero barriers / zero LDS traffic in the loop.
// launch_bounds(512,2): R4 PROVED (512,4) caps VGPR at 64 -> af[4][8] spills
// to scratch (WRITE_SIZE 53MB, FETCH 443MB, MfmaUtil 7%). (512,2) -> ~100-140
// VGPR, no spill (R2/R3 precedent).
__global__ __launch_bounds__(512, 2) void
k_gemm(const unsigned short* __restrict__ A, const unsigned short* __restrict__ embbf,
       const float* __restrict__ enorm, const float* __restrict__ xn_g,
       unsigned* __restrict__ keys_g, float* __restrict__ out,
       float* __restrict__ loss, unsigned* __restrict__ ctr) {
  __shared__ float    cjl[1024];
  __shared__ unsigned keys_l[128];
  __shared__ float    xn_l[128];
  __shared__ float    red[8];

  int n0 = blockIdx.x * 128;
  int t = threadIdx.x, w = t >> 6, lane = t & 63;
  int quad = lane >> 4, lr = lane & 15;
  int g  = w >> 2;       // n-group 0..1 (64 n)
  int h2 = w & 3;        // k-quarter (16 of each 64-k tile)

  for (int i = t; i < 1024; i += 512) cjl[i] = 0.375f - 0.5f * enorm[i];
  if (t < 128) { keys_l[t] = 0u; xn_l[t] = xn_g[n0 + t]; }

  // ---- A fragments direct from global (one-shot, 64KB/block from L3/L2) ----
  bf16x8 af[4][8];
#pragma unroll
  for (int i = 0; i < 4; ++i) {
    const unsigned short* ar =
        A + (size_t)(n0 + g * 64 + i * 16 + lr) * EMB_C + quad * 8;
#pragma unroll
    for (int s = 0; s < 8; ++s)
      af[i][s] = *(const bf16x8*)(ar + s * 32);   // col = s*32 + quad*8
  }
  __syncthreads();   // cjl / keys_l / xn_l visible

  // ---- K-loop: 16 tiles of 64 emb rows, fully wave-independent ----
  unsigned best[4][4] = {};
  const unsigned short* bbase = embbf + (size_t)(h2 * 16 + lr) * EMB_C + quad * 8;
  for (int kt = 0; kt < 16; ++kt) {
    const unsigned short* br = bbase + (size_t)kt * 64 * EMB_C;
    int k = kt * 64 + h2 * 16 + lr;
    float cj = cjl[k];
    unsigned kp = 1023u - (unsigned)k;
    f32x4 acc[4] = {};
#pragma unroll
    for (int s = 0; s < 8; ++s) {
      bf16x8 bf = *(const bf16x8*)(br + s * 32);  // B[k][s*32+quad*8 ..]
#pragma unroll
      for (int i = 0; i < 4; ++i)
        acc[i] = __builtin_amdgcn_mfma_f32_16x16x32_bf16(af[i][s], bf, acc[i], 0, 0, 0);
    }
    // fold argmin keys: f = dot + 0.375 - 0.5||e||^2 in (0.04,0.71) -> positive
    // float u32-order-correct; low 10 mantissa bits carry (1023-k).
#pragma unroll
    for (int i = 0; i < 4; ++i)
#pragma unroll
      for (int r = 0; r < 4; ++r) {
        float f = acc[i][r] + cj;
        unsigned key = (__float_as_uint(f) & 0xFFFFFC00u) | kp;
        best[i][r] = best[i][r] > key ? best[i][r] : key;
      }
  }
  __syncthreads();   // k-loop complete before keys_l atomics phase

  // ---- combine keys across k-lanes; k-quarters via LDS atomicMax ----
#pragma unroll
  for (int i = 0; i < 4; ++i)
#pragma unroll
    for (int r = 0; r < 4; ++r) {
      unsigned v = best[i][r];
#pragma unroll
      for (int m = 1; m < 16; m <<= 1) {
        unsigned o = (unsigned)__shfl_xor((int)v, m, 64);
        v = v > o ? v : o;
      }
      if (lr == 0) atomicMax(&keys_l[g * 64 + i * 16 + quad * 4 + r], v);
    }
  __syncthreads();

  // ---- keys export + loss partial: d2 = ||x||^2 + 0.75 - 2*f_hat ----
  if (t < 128) {
    unsigned key = keys_l[t];
    keys_g[n0 + t] = key;
    float fh = __uint_as_float(key & 0xFFFFFC00u);
    float lsum = xn_l[t] + 0.75f - 2.0f * fh;
    for (int m = 32; m; m >>= 1) lsum += __shfl_down(lsum, m, 64);
    if (lane == 0) red[w] = lsum;
  }
  __syncthreads();
  if (t == 0) {
    atomicAdd(loss, red[0] + red[1]);
    __threadfence();
    unsigned done = atomicAdd(ctr, 1u);
    if (done == gridDim.x - 1) {
      float total = atomicAdd(loss, 0.f);   // device-scope read of final sum
      out[0] = 1.0625f * total / 16777216.0f;
    }
  }
}

// ---- K3: gather emb rows -> LDS [64c][256n] -> 1KB/wave contiguous stores ----
__global__ __launch_bounds__(512) void
k_out(const float* __restrict__ emb, const unsigned* __restrict__ keys_g,
      float* __restrict__ out) {
  extern __shared__ float tile[];            // 64 x 256 f32 = 64 KB
  int t  = threadIdx.x;
  int n0 = blockIdx.x * 256;
  int b  = n0 >> 12, hw0 = n0 & 4095;
  int w  = t >> 6, lane = t & 63;
  int n  = t >> 1, ch = t & 1;               // thread pair per n
  int idx = 1023 - (int)(keys_g[n0 + n] & 1023u);
  const float* er = emb + (size_t)idx * EMB_C;
  float* ob = out + 1 + (size_t)b * (EMB_C * HWB) + hw0;
  for (int p = 0; p < 4; ++p) {
    int c0 = p * 64;
    if (p) __syncthreads();
#pragma unroll
    for (int jj = 0; jj < 8; ++jj) {         // 8 x 16B L2-resident gathers
      f32x4 q = *(const f32x4*)(er + c0 + ch * 32 + jj * 4);
#pragma unroll
      for (int m = 0; m < 4; ++m)
        tile[(ch * 32 + jj * 4 + m) * 256 + n] = q[m];
    }
    __syncthreads();
#pragma unroll
    for (int cc = 0; cc < 8; ++cc) {         // wave w: c-rows w*8..w*8+7
      int cl = w * 8 + cc;
      f32x4 q = *(const f32x4*)(tile + cl * 256 + lane * 4);
      *(f32x4a*)(ob + (size_t)(c0 + cl) * HWB + lane * 4) = q;  // 1KB/wave
    }
  }
}

extern "C" void kernel_launch(void* const* d_in, const int* in_sizes, int n_in,
                              void* d_out, int out_size, void* d_ws, size_t ws_size,
                              hipStream_t stream) {
  const float* x   = (const float*)d_in[0];   // [16,256,64,64]
  const float* emb = (const float*)d_in[1];   // [1024,256]
  float* out = (float*)d_out;                 // [1 + 16777216]
  char*  ws  = (char*)d_ws;

  unsigned short* emb_bf = (unsigned short*)ws;                 // 512 KB
  float*          enorm  = (float*)(ws + 524288);               // 4 KB
  float*          loss   = (float*)(ws + 528384);               // 4 B
  unsigned*       ctr    = (unsigned*)(ws + 528388);            // 4 B
  float*          xn_g   = (float*)(ws + 532480);               // 256 KB
  unsigned*       keys_g = (unsigned*)(ws + 794624);            // 256 KB

  // A (bf16 [65536][256], 32 MB) lives inside the out payload, 16B-aligned at
  // out+4 floats. K2 reads it before K3 overwrites out[1..] (stream-ordered).
  unsigned short* A = (unsigned short*)(out + 4);

  hipFuncSetAttribute((const void*)k_out,
                      hipFuncAttributeMaxDynamicSharedMemorySize, 65536);

  k_emb <<<dim3(EMB_K),      dim3(EMB_C), 0,     stream>>>(emb, emb_bf, enorm, loss, ctr);
  k_tr  <<<dim3(NPIX / 64),  dim3(256),   0,     stream>>>(x, A, xn_g);
  k_gemm<<<dim3(NPIX / 128), dim3(512),   0,     stream>>>(A, emb_bf, enorm, xn_g,
                                                           keys_g, out, loss, ctr);
  k_out <<<dim3(NPIX / 256), dim3(512),   65536, stream>>>(emb, keys_g, out);
}

// Round 6
// 209.142 us; speedup vs baseline: 1.5409x; 1.0878x over previous
//
#include <hip/hip_runtime.h>
#include <hip/hip_bf16.h>
#include <cstdint>
#include <cstddef>

#define EMB_K   1024
#define EMB_C   256
#define HWB     4096        // 64*64 per batch
#define NPIX    65536       // 16*4096

typedef __bf16 bf16x8 __attribute__((ext_vector_type(8)));
typedef float  f32x4  __attribute__((ext_vector_type(4)));
// 4-byte-aligned variant for the out+1 (4 mod 16) store path
typedef float  f32x4a __attribute__((ext_vector_type(4), aligned(4)));

__device__ __forceinline__ unsigned short bf16bits(float v) {
  __hip_bfloat16 h = __float2bfloat16(v);
  return __builtin_bit_cast(unsigned short, h);
}

// ---- emb -> bf16 (FRAGMENT-PERMUTED layout) + fp32 norms; zero loss/ctr ----
// Permuted so k_gemm's per-wave B-fragment load for (kt,h2,s) is 64 lanes x
// consecutive 16B = one fully-coalesced 1KB instruction (R5 was 16 txn/instr).
// Element (k,c) -> shorts offset (kt*4+h2)*4096 + s*512 + (quad*16+lr)*8 + j
// where kt=k>>6, h2=(k>>4)&3, lr=k&15, s=c>>5, quad=(c>>3)&3, j=c&7.
__global__ void k_emb(const float* __restrict__ emb, unsigned short* __restrict__ emb_bf,
                      float* __restrict__ enorm, float* __restrict__ loss,
                      unsigned* __restrict__ ctr) {
  int k = blockIdx.x;      // 0..1023
  int c = threadIdx.x;     // 0..255
  if (k == 0 && c == 0) { *loss = 0.f; *ctr = 0u; }
  float v = emb[(size_t)k * EMB_C + c];
  int kt = k >> 6, h2 = (k >> 4) & 3, lr = k & 15;
  int s = c >> 5, quad = (c >> 3) & 3, j = c & 7;
  emb_bf[(size_t)(kt * 4 + h2) * 4096 + s * 512 + (quad * 16 + lr) * 8 + j] = bf16bits(v);
  float sq = v * v;
  for (int m = 32; m; m >>= 1) sq += __shfl_down(sq, m, 64);
  __shared__ float red[4];
  int lane = c & 63, w = c >> 6;
  if (lane == 0) red[w] = sq;
  __syncthreads();
  if (c == 0) enorm[k] = red[0] + red[1] + red[2] + red[3];
}

// ---- K1: x[b][c][hw] -> A[n][c] bf16 (row-major, 512B rows) + xn f32 ----
__global__ __launch_bounds__(256) void
k_tr(const float* __restrict__ x, unsigned short* __restrict__ A,
     float* __restrict__ xn_g) {
  __shared__ unsigned char tile[64 * 512];   // 32 KB
  __shared__ float xn_l[64];
  int t  = threadIdx.x;
  int n0 = blockIdx.x * 64;
  int b  = n0 >> 12, hw0 = n0 & 4095;
  int nl = t & 63, qq = t >> 6;              // qq = c-quarter 0..3
  if (t < 64) xn_l[t] = 0.f;
  __syncthreads();
  const float* xp = x + (size_t)b * (EMB_C * HWB) + hw0 + nl;
  float xn = 0.f;
#pragma unroll
  for (int o = 0; o < 8; ++o) {
    int cc = qq * 8 + o;                     // c-chunk 0..31 (8 c each)
    float v[8];
#pragma unroll
    for (int j = 0; j < 8; ++j) {
      v[j] = xp[(size_t)(cc * 8 + j) * HWB]; // 256B-coalesced per instr
      xn += v[j] * v[j];
    }
    union { unsigned u[4]; uint4 q; } pk;
#pragma unroll
    for (int m = 0; m < 4; ++m)
      pk.u[m] = (unsigned)bf16bits(v[2 * m]) | ((unsigned)bf16bits(v[2 * m + 1]) << 16);
    int pos = ((cc >> 3) << 3) | ((cc & 7) ^ (nl & 7));
    *(uint4*)(tile + nl * 512 + pos * 16) = pk.q;
  }
  atomicAdd(&xn_l[nl], xn);                  // 4 partials per n
  __syncthreads();
  if (t < 64) xn_g[n0 + t] = xn_l[t];
  uint4* Adst = (uint4*)A + (size_t)n0 * 32; // 32 x 16B chunks per row
#pragma unroll
  for (int k = 0; k < 8; ++k) {
    int id = k * 256 + t;                    // chunk 0..2047 (64 rows x 32)
    int n = id >> 5, slot = id & 31;
    int pos = ((slot >> 3) << 3) | ((slot & 7) ^ (n & 7));
    Adst[id] = *(const uint4*)(tile + n * 512 + pos * 16);  // 1KB/wave stores
  }
}

// ---- K2: GEMM + argmin + loss. 512 blocks x 512 thr. ----
// Barrier-free reg-streamed k-loop (R4/R5 structure) with COALESCED B loads
// from the fragment-permuted embbf: each (kt,s) load = 1KB contiguous per
// wave, values identical to the row-major path. No barriers / no LDS traffic
// in the loop; compiler pipelines loads under MFMA.
// launch_bounds(512,2): (512,4) caps VGPR at 64 -> af spills (R4: 53MB
// scratch writes, MfmaUtil 7%). Keep 2 -> VGPR ~92-100, no spill.
__global__ __launch_bounds__(512, 2) void
k_gemm(const unsigned short* __restrict__ A, const unsigned short* __restrict__ embbf,
       const float* __restrict__ enorm, const float* __restrict__ xn_g,
       unsigned* __restrict__ keys_g, float* __restrict__ out,
       float* __restrict__ loss, unsigned* __restrict__ ctr) {
  __shared__ float    cjl[1024];
  __shared__ unsigned keys_l[128];
  __shared__ float    xn_l[128];
  __shared__ float    red[8];

  int n0 = blockIdx.x * 128;
  int t = threadIdx.x, w = t >> 6, lane = t & 63;
  int quad = lane >> 4, lr = lane & 15;
  int g  = w >> 2;       // n-group 0..1 (64 n)
  int h2 = w & 3;        // k-quarter (16 of each 64-k tile)

  for (int i = t; i < 1024; i += 512) cjl[i] = 0.375f - 0.5f * enorm[i];
  if (t < 128) { keys_l[t] = 0u; xn_l[t] = xn_g[n0 + t]; }

  // ---- A fragments direct from global (one-shot, 64KB/block from L3/L2) ----
  bf16x8 af[4][8];
#pragma unroll
  for (int i = 0; i < 4; ++i) {
    const unsigned short* ar =
        A + (size_t)(n0 + g * 64 + i * 16 + lr) * EMB_C + quad * 8;
#pragma unroll
    for (int s = 0; s < 8; ++s)
      af[i][s] = *(const bf16x8*)(ar + s * 32);   // col = s*32 + quad*8
  }
  __syncthreads();   // cjl / keys_l / xn_l visible

  // ---- K-loop: 16 tiles of 64 emb rows, fully wave-independent ----
  unsigned best[4][4] = {};
  // permuted embbf: (kt*4+h2)*4096 + s*512 + lane*8  (shorts)
  const unsigned short* bbase = embbf + (size_t)h2 * 4096 + lane * 8;
  for (int kt = 0; kt < 16; ++kt) {
    const unsigned short* br = bbase + (size_t)kt * 16384;
    int k = kt * 64 + h2 * 16 + lr;
    float cj = cjl[k];
    unsigned kp = 1023u - (unsigned)k;
    f32x4 acc[4] = {};
#pragma unroll
    for (int s = 0; s < 8; ++s) {
      bf16x8 bf = *(const bf16x8*)(br + s * 512);  // 1KB coalesced per wave
#pragma unroll
      for (int i = 0; i < 4; ++i)
        acc[i] = __builtin_amdgcn_mfma_f32_16x16x32_bf16(af[i][s], bf, acc[i], 0, 0, 0);
    }
    // fold argmin keys: f = dot + 0.375 - 0.5||e||^2 in (0.04,0.71) -> positive
    // float u32-order-correct; low 10 mantissa bits carry (1023-k).
#pragma unroll
    for (int i = 0; i < 4; ++i)
#pragma unroll
      for (int r = 0; r < 4; ++r) {
        float f = acc[i][r] + cj;
        unsigned key = (__float_as_uint(f) & 0xFFFFFC00u) | kp;
        best[i][r] = best[i][r] > key ? best[i][r] : key;
      }
  }
  __syncthreads();   // k-loop complete before keys_l atomics phase

  // ---- combine keys across k-lanes; k-quarters via LDS atomicMax ----
#pragma unroll
  for (int i = 0; i < 4; ++i)
#pragma unroll
    for (int r = 0; r < 4; ++r) {
      unsigned v = best[i][r];
#pragma unroll
      for (int m = 1; m < 16; m <<= 1) {
        unsigned o = (unsigned)__shfl_xor((int)v, m, 64);
        v = v > o ? v : o;
      }
      if (lr == 0) atomicMax(&keys_l[g * 64 + i * 16 + quad * 4 + r], v);
    }
  __syncthreads();

  // ---- keys export + loss partial: d2 = ||x||^2 + 0.75 - 2*f_hat ----
  if (t < 128) {
    unsigned key = keys_l[t];
    keys_g[n0 + t] = key;
    float fh = __uint_as_float(key & 0xFFFFFC00u);
    float lsum = xn_l[t] + 0.75f - 2.0f * fh;
    for (int m = 32; m; m >>= 1) lsum += __shfl_down(lsum, m, 64);
    if (lane == 0) red[w] = lsum;
  }
  __syncthreads();
  if (t == 0) {
    atomicAdd(loss, red[0] + red[1]);
    __threadfence();
    unsigned done = atomicAdd(ctr, 1u);
    if (done == gridDim.x - 1) {
      float total = atomicAdd(loss, 0.f);   // device-scope read of final sum
      out[0] = 1.0625f * total / 16777216.0f;
    }
  }
}

// ---- K3: gather emb rows -> LDS [64c][256n] -> 1KB/wave contiguous stores ----
__global__ __launch_bounds__(512) void
k_out(const float* __restrict__ emb, const unsigned* __restrict__ keys_g,
      float* __restrict__ out) {
  extern __shared__ float tile[];            // 64 x 256 f32 = 64 KB
  int t  = threadIdx.x;
  int n0 = blockIdx.x * 256;
  int b  = n0 >> 12, hw0 = n0 & 4095;
  int w  = t >> 6, lane = t & 63;
  int n  = t >> 1, ch = t & 1;               // thread pair per n
  int idx = 1023 - (int)(keys_g[n0 + n] & 1023u);
  const float* er = emb + (size_t)idx * EMB_C;
  float* ob = out + 1 + (size_t)b * (EMB_C * HWB) + hw0;
  for (int p = 0; p < 4; ++p) {
    int c0 = p * 64;
    if (p) __syncthreads();
#pragma unroll
    for (int jj = 0; jj < 8; ++jj) {         // 8 x 16B L2-resident gathers
      f32x4 q = *(const f32x4*)(er + c0 + ch * 32 + jj * 4);
#pragma unroll
      for (int m = 0; m < 4; ++m)
        tile[(ch * 32 + jj * 4 + m) * 256 + n] = q[m];
    }
    __syncthreads();
#pragma unroll
    for (int cc = 0; cc < 8; ++cc) {         // wave w: c-rows w*8..w*8+7
      int cl = w * 8 + cc;
      f32x4 q = *(const f32x4*)(tile + cl * 256 + lane * 4);
      *(f32x4a*)(ob + (size_t)(c0 + cl) * HWB + lane * 4) = q;  // 1KB/wave
    }
  }
}

extern "C" void kernel_launch(void* const* d_in, const int* in_sizes, int n_in,
                              void* d_out, int out_size, void* d_ws, size_t ws_size,
                              hipStream_t stream) {
  const float* x   = (const float*)d_in[0];   // [16,256,64,64]
  const float* emb = (const float*)d_in[1];   // [1024,256]
  float* out = (float*)d_out;                 // [1 + 16777216]
  char*  ws  = (char*)d_ws;

  unsigned short* emb_bf = (unsigned short*)ws;                 // 512 KB (permuted)
  float*          enorm  = (float*)(ws + 524288);               // 4 KB
  float*          loss   = (float*)(ws + 528384);               // 4 B
  unsigned*       ctr    = (unsigned*)(ws + 528388);            // 4 B
  float*          xn_g   = (float*)(ws + 532480);               // 256 KB
  unsigned*       keys_g = (unsigned*)(ws + 794624);            // 256 KB

  // A (bf16 [65536][256], 32 MB) lives inside the out payload, 16B-aligned at
  // out+4 floats. K2 reads it before K3 overwrites out[1..] (stream-ordered).
  unsigned short* A = (unsigned short*)(out + 4);

  hipFuncSetAttribute((const void*)k_out,
                      hipFuncAttributeMaxDynamicSharedMemorySize, 65536);

  k_emb <<<dim3(EMB_K),      dim3(EMB_C), 0,     stream>>>(emb, emb_bf, enorm, loss, ctr);
  k_tr  <<<dim3(NPIX / 64),  dim3(256),   0,     stream>>>(x, A, xn_g);
  k_gemm<<<dim3(NPIX / 128), dim3(512),   0,     stream>>>(A, emb_bf, enorm, xn_g,
                                                           keys_g, out, loss, ctr);
  k_out <<<dim3(NPIX / 256), dim3(512),   65536, stream>>>(emb, keys_g, out);
}

// Round 7
// 207.473 us; speedup vs baseline: 1.5533x; 1.0080x over previous
//
#include <hip/hip_runtime.h>
#include <hip/hip_bf16.h>
#include <cstdint>
#include <cstddef>

#define EMB_K   1024
#define EMB_C   256
#define HWB     4096        // 64*64 per batch
#define NPIX    65536       // 16*4096

typedef __bf16 bf16x8 __attribute__((ext_vector_type(8)));
typedef float  f32x4  __attribute__((ext_vector_type(4)));
// 4-byte-aligned variant for the out+1 (4 mod 16) store path
typedef float  f32x4a __attribute__((ext_vector_type(4), aligned(4)));

__device__ __forceinline__ unsigned short bf16bits(float v) {
  __hip_bfloat16 h = __float2bfloat16(v);
  return __builtin_bit_cast(unsigned short, h);
}

// ---- emb -> bf16 ROW-MAJOR (glds staging needs linear rows) + norms ----
__global__ void k_emb(const float* __restrict__ emb, unsigned short* __restrict__ emb_bf,
                      float* __restrict__ enorm, float* __restrict__ loss,
                      unsigned* __restrict__ ctr) {
  int k = blockIdx.x;      // 0..1023
  int c = threadIdx.x;     // 0..255
  if (k == 0 && c == 0) { *loss = 0.f; *ctr = 0u; }
  float v = emb[(size_t)k * EMB_C + c];
  emb_bf[(size_t)k * EMB_C + c] = bf16bits(v);
  float s = v * v;
  for (int m = 32; m; m >>= 1) s += __shfl_down(s, m, 64);
  __shared__ float red[4];
  int lane = c & 63, w = c >> 6;
  if (lane == 0) red[w] = s;
  __syncthreads();
  if (c == 0) enorm[k] = red[0] + red[1] + red[2] + red[3];
}

// ---- staging: 64 rows x 256c bf16 = 32KB, XOR-swizzled 16B chunks, glds ----
__device__ __forceinline__ void stage64(const unsigned short* __restrict__ rows,
                                        unsigned char* buf, int t) {
#pragma unroll
  for (int j = 0; j < 4; ++j) {
    int d = j * 512 + t;             // linear dest chunk 0..2047
    int r = d >> 5;                  // row 0..63
    int slot = d & 31;
    int c16 = ((slot >> 3) << 3) | ((slot & 7) ^ (r & 7));
    const unsigned short* src = rows + (size_t)r * EMB_C + c16 * 8;
    __builtin_amdgcn_global_load_lds(
        (const __attribute__((address_space(1))) void*)src,
        (__attribute__((address_space(3))) void*)(buf + (unsigned)(j * 8192 + (t >> 6) * 1024)),
        16, 0, 0);
  }
}

// ================= fused main kernel =================
// 256 blocks x 512 thr, 1 block/CU (134KB LDS). Block owns 256 n (one b) and
// all 1024 k. Everything in-block: transpose -> af regs -> pipelined GEMM ->
// argmin -> loss -> output. Waves: g=w>>1 n-group (64n), h2=w&1 k-half (32k of
// each 64k tile). A (64n x 256c) in af[4][8] regs; B in a 4-buffer LDS
// rotation: per k-tile ONE s_barrier + counted vmcnt(8) — each stage is
// issued 2 MFMA-phases before its wait (issue-early/wait-late), unlike the
// R2/R3 structures that drained just-issued stages (the measured 56-62us
// ceiling). Buffer safety: stage(kt+2) targets buf[(kt+2)&3], distinct mod 4
// from buf[kt&3]/buf[(kt-1)&3] that any wave may still read one barrier
// behind; per-wave vmcnt(8) before the barrier => all stage(kt) chunks landed
// before any read of buf[kt&3].
// LDS: [0,128K) bufs 4x32KB | cjl 4KB | keys_l 1KB | xn_l 1KB | red
#define LDS_BYTES 137280

__global__ __launch_bounds__(512, 1) void
k_main(const float* __restrict__ x, const float* __restrict__ emb,
       const unsigned short* __restrict__ embbf, const float* __restrict__ enorm,
       float* __restrict__ out, float* __restrict__ loss, unsigned* __restrict__ ctr) {
  extern __shared__ char smem[];
  float*    cjl    = (float*)(smem + 131072);          // 1024 f32
  unsigned* keys_l = (unsigned*)(smem + 135168);       // 256 u32
  float*    xn_l   = (float*)(smem + 136192);          // 256 f32
  float*    red    = (float*)(smem + 137216);          // 16 f32

  int n0 = blockIdx.x * 256;
  int b  = n0 >> 12, hw0 = n0 & 4095;
  int t = threadIdx.x, w = t >> 6, lane = t & 63;
  int quad = lane >> 4, lr = lane & 15;
  int g  = w >> 1;       // n-group 0..3 (64 n)
  int h2 = w & 1;        // k-half (32 k of each 64k tile)

  for (int i = t; i < 1024; i += 512) cjl[i] = 0.375f - 0.5f * enorm[i];
  if (t < 256) { keys_l[t] = 0u; xn_l[t] = 0.f; }
  __syncthreads();

  // ---- prologue: transpose 256 n in 2 passes of 128 through a 64KB tile ----
  bf16x8 af[4][8];
#pragma unroll
  for (int p = 0; p < 2; ++p) {
    if (p) __syncthreads();            // pass-0 af-reads done before rewrite
    {
      int nl = ((t >> 6) & 1) * 64 + lane;   // n-local-in-pass 0..127
      const float* xp = x + (size_t)b * (EMB_C * HWB) + hw0 + p * 128 + nl;
      float xn = 0.f;
#pragma unroll
      for (int o = 0; o < 8; ++o) {
        int cc = (t >> 7) * 8 + o;           // c-chunk 0..31 (8 c each)
        float v[8];
#pragma unroll
        for (int j = 0; j < 8; ++j) {
          v[j] = xp[(size_t)(cc * 8 + j) * HWB];   // 256B-coalesced per instr
          xn += v[j] * v[j];
        }
        union { unsigned u[4]; uint4 q; } pk;
#pragma unroll
        for (int m = 0; m < 4; ++m)
          pk.u[m] = (unsigned)bf16bits(v[2 * m]) | ((unsigned)bf16bits(v[2 * m + 1]) << 16);
        int pos = ((cc >> 3) << 3) | ((cc & 7) ^ (nl & 7));
        *(uint4*)(smem + nl * 512 + pos * 16) = pk.q;
      }
      atomicAdd(&xn_l[p * 128 + nl], xn);    // 4 partials per n
    }
    __syncthreads();
    if ((g >> 1) == p) {                     // waves of this pass load af
#pragma unroll
      for (int i = 0; i < 4; ++i) {
        int rA = (g & 1) * 64 + i * 16 + lr;
#pragma unroll
        for (int s = 0; s < 8; ++s) {
          int cc = s * 4 + quad;
          int pos = ((cc >> 3) << 3) | ((cc & 7) ^ (rA & 7));
          af[i][s] = *(const bf16x8*)(smem + rA * 512 + pos * 16);
        }
      }
    }
  }
  __syncthreads();   // af complete; [0,128K) becomes the B rotation

  // ---- pipelined K-loop: 16 tiles of 64 k, 4-buf, 1 barrier/tile ----
  stage64(embbf,                (unsigned char*)smem,         t);   // buf0
  stage64(embbf + 64 * EMB_C,   (unsigned char*)smem + 32768, t);   // buf1
  unsigned best[4][4] = {};
#pragma unroll
  for (int kt = 0; kt < 16; ++kt) {
    if (kt < 14)
      stage64(embbf + (size_t)(kt + 2) * 64 * EMB_C,
              (unsigned char*)smem + (((kt + 2) & 3) << 15), t);
    if (kt < 14)       asm volatile("s_waitcnt vmcnt(8)" ::: "memory");
    else if (kt == 14) asm volatile("s_waitcnt vmcnt(4)" ::: "memory");
    else               asm volatile("s_waitcnt vmcnt(0)" ::: "memory");
    __builtin_amdgcn_s_barrier();
    const unsigned char* sb = (const unsigned char*)smem + ((kt & 3) << 15);
    int k0 = kt * 64 + h2 * 32 + lr;
    float cj0 = cjl[k0], cj1 = cjl[k0 + 16];
    unsigned kp0 = 1023u - (unsigned)k0, kp1 = kp0 - 16u;
    f32x4 a0[4] = {}, a1[4] = {};
#pragma unroll
    for (int s = 0; s < 8; ++s) {
      int cc = s * 4 + quad;
      int pos = ((cc >> 3) << 3) | ((cc & 7) ^ (lr & 7));  // rB&7 == lr&7
      bf16x8 b0 = *(const bf16x8*)(sb + (h2 * 32 + lr) * 512 + pos * 16);
      bf16x8 b1 = *(const bf16x8*)(sb + (h2 * 32 + 16 + lr) * 512 + pos * 16);
#pragma unroll
      for (int i = 0; i < 4; ++i) {
        a0[i] = __builtin_amdgcn_mfma_f32_16x16x32_bf16(af[i][s], b0, a0[i], 0, 0, 0);
        a1[i] = __builtin_amdgcn_mfma_f32_16x16x32_bf16(af[i][s], b1, a1[i], 0, 0, 0);
      }
    }
    // fold argmin keys: f = dot + 0.375 - 0.5||e||^2 in (0.04,0.71) -> positive
    // float u32-order-correct; low 10 mantissa bits carry (1023-k).
#pragma unroll
    for (int i = 0; i < 4; ++i)
#pragma unroll
      for (int r = 0; r < 4; ++r) {
        float f0 = a0[i][r] + cj0;
        unsigned key0 = (__float_as_uint(f0) & 0xFFFFFC00u) | kp0;
        best[i][r] = best[i][r] > key0 ? best[i][r] : key0;
        float f1 = a1[i][r] + cj1;
        unsigned key1 = (__float_as_uint(f1) & 0xFFFFFC00u) | kp1;
        best[i][r] = best[i][r] > key1 ? best[i][r] : key1;
      }
  }
  __syncthreads();   // k-loop complete before keys_l atomics phase

  // ---- combine keys across k-lanes; k-halves/waves via LDS atomicMax ----
#pragma unroll
  for (int i = 0; i < 4; ++i)
#pragma unroll
    for (int r = 0; r < 4; ++r) {
      unsigned v = best[i][r];
#pragma unroll
      for (int m = 1; m < 16; m <<= 1) {
        unsigned o = (unsigned)__shfl_xor((int)v, m, 64);
        v = v > o ? v : o;
      }
      if (lr == 0) atomicMax(&keys_l[g * 64 + i * 16 + quad * 4 + r], v);
    }
  __syncthreads();

  // ---- loss partial: d2 = ||x||^2 + 0.75 - 2*f_hat ----
  if (t < 256) {
    unsigned key = keys_l[t];
    float fh = __uint_as_float(key & 0xFFFFFC00u);
    float lsum = xn_l[t] + 0.75f - 2.0f * fh;
    for (int m = 32; m; m >>= 1) lsum += __shfl_down(lsum, m, 64);
    if (lane == 0) red[w] = lsum;
  }
  __syncthreads();
  if (t == 0) {
    atomicAdd(loss, red[0] + red[1] + red[2] + red[3]);
    __threadfence();
  }

  // ---- output: gather emb rows -> LDS [64c][256n] -> 1KB/wave stores ----
  float* tile = (float*)smem;
  int n  = t >> 1, ch = t & 1;               // thread pair per n
  int idx = 1023 - (int)(keys_l[n] & 1023u);
  const float* er = emb + (size_t)idx * EMB_C;
  float* ob = out + 1 + (size_t)b * (EMB_C * HWB) + hw0;
  for (int p = 0; p < 4; ++p) {
    int c0 = p * 64;
    if (p) __syncthreads();
#pragma unroll
    for (int jj = 0; jj < 8; ++jj) {         // 8 x 16B L2-resident gathers
      f32x4 q = *(const f32x4*)(er + c0 + ch * 32 + jj * 4);
#pragma unroll
      for (int m = 0; m < 4; ++m)
        tile[(ch * 32 + jj * 4 + m) * 256 + n] = q[m];
    }
    __syncthreads();
#pragma unroll
    for (int cc = 0; cc < 8; ++cc) {         // wave w: c-rows w*8..w*8+7
      int cl = w * 8 + cc;
      f32x4 q = *(const f32x4*)(tile + cl * 256 + lane * 4);
      *(f32x4a*)(ob + (size_t)(c0 + cl) * HWB + lane * 4) = q;  // 1KB/wave
    }
  }

  // ---- fused finalize: last block writes out[0] ----
  if (t == 0) {
    unsigned done = atomicAdd(ctr, 1u);
    if (done == gridDim.x - 1) {
      float total = atomicAdd(loss, 0.f);   // device-scope read of final sum
      out[0] = 1.0625f * total / 16777216.0f;
    }
  }
}

extern "C" void kernel_launch(void* const* d_in, const int* in_sizes, int n_in,
                              void* d_out, int out_size, void* d_ws, size_t ws_size,
                              hipStream_t stream) {
  const float* x   = (const float*)d_in[0];   // [16,256,64,64]
  const float* emb = (const float*)d_in[1];   // [1024,256]
  float* out = (float*)d_out;                 // [1 + 16777216]
  char*  ws  = (char*)d_ws;

  unsigned short* emb_bf = (unsigned short*)ws;                 // 512 KB
  float*          enorm  = (float*)(ws + 524288);               // 4 KB
  float*          loss   = (float*)(ws + 528384);               // 4 B
  unsigned*       ctr    = (unsigned*)(ws + 528388);            // 4 B

  // allow >64KB dynamic LDS (idempotent, capture-safe — proven pattern)
  hipFuncSetAttribute((const void*)k_main,
                      hipFuncAttributeMaxDynamicSharedMemorySize, LDS_BYTES);

  k_emb <<<dim3(EMB_K),      dim3(EMB_C), 0,         stream>>>(emb, emb_bf, enorm, loss, ctr);
  k_main<<<dim3(NPIX / 256), dim3(512),   LDS_BYTES, stream>>>(x, emb, emb_bf, enorm,
                                                               out, loss, ctr);
}

// Round 8
// 159.949 us; speedup vs baseline: 2.0148x; 1.2971x over previous
//
#include <hip/hip_runtime.h>
#include <hip/hip_bf16.h>
#include <cstdint>
#include <cstddef>

#define EMB_K   1024
#define EMB_C   256
#define HWB     4096        // 64*64 per batch
#define NPIX    65536       // 16*4096

typedef __bf16 bf16x8 __attribute__((ext_vector_type(8)));
typedef float  f32x4  __attribute__((ext_vector_type(4)));

__device__ __forceinline__ unsigned short bf16bits(float v) {
  __hip_bfloat16 h = __float2bfloat16(v);
  return __builtin_bit_cast(unsigned short, h);
}

// ---- emb -> bf16 row-major + fp32 norms; zero loss + ctr ----
__global__ void k_emb(const float* __restrict__ emb, unsigned short* __restrict__ emb_bf,
                      float* __restrict__ enorm, float* __restrict__ loss,
                      unsigned* __restrict__ ctr) {
  int k = blockIdx.x;      // 0..1023
  int c = threadIdx.x;     // 0..255
  if (k == 0 && c == 0) { *loss = 0.f; *ctr = 0u; }
  float v = emb[(size_t)k * EMB_C + c];
  emb_bf[(size_t)k * EMB_C + c] = bf16bits(v);
  float s = v * v;
  for (int m = 32; m; m >>= 1) s += __shfl_down(s, m, 64);
  __shared__ float red[4];
  int lane = c & 63, w = c >> 6;
  if (lane == 0) red[w] = s;
  __syncthreads();
  if (c == 0) enorm[k] = red[0] + red[1] + red[2] + red[3];
}

// ---- staging: 64 rows x 256c bf16 = 32KB, XOR-swizzled 16B chunks, glds ----
// 1024-thread variant: 2048 chunks, 2 per thread. dest = wave-uniform base +
// lane*16 (glds constraint); chunk d -> buf + (j*1024 + wave*64)*16.
__device__ __forceinline__ void stage64b(const unsigned short* __restrict__ rows,
                                         unsigned char* buf, int t) {
#pragma unroll
  for (int j = 0; j < 2; ++j) {
    int d = j * 1024 + t;            // linear dest chunk 0..2047
    int r = d >> 5;                  // row 0..63
    int slot = d & 31;
    int c16 = ((slot >> 3) << 3) | ((slot & 7) ^ (r & 7));
    const unsigned short* src = rows + (size_t)r * EMB_C + c16 * 8;
    __builtin_amdgcn_global_load_lds(
        (const __attribute__((address_space(1))) void*)src,
        (__attribute__((address_space(3))) void*)(buf + (unsigned)(j * 16384 + (t >> 6) * 1024)),
        16, 0, 0);
  }
}

// ================= fused main kernel =================
// 256 blocks x 1024 thr, 1 block/CU (70KB LDS, VGPR<=128 -> 16 waves). Block
// owns 256 n (one b, 256 consecutive hw) and all 1024 k. Waves (16): g=w>>1
// n-group (32n), h2=w&1 k-half (32k of each 64k tile). af[2][8]=64 VGPR per
// wave (spill-proof: total live ~110 < 128 cap implied by 1024-thr block).
// All hot global paths are 16B/lane: prologue float4 x-reads, glds B staging,
// epilogue aligned-f32x4 stores (rotate-by-3 LDS layout absorbs the out+1
// misalignment). K-loop keeps R1's proven 2-barrier double-buffer.
// LDS: [0,64K) A-tile then B ping/pong | cjl 4K | keys 1K | xn 1K | red
#define LDS_BYTES 71744

__global__ __launch_bounds__(1024) void
k_main(const float* __restrict__ x, const float* __restrict__ emb,
       const unsigned short* __restrict__ embbf, const float* __restrict__ enorm,
       float* __restrict__ out, float* __restrict__ loss, unsigned* __restrict__ ctr) {
  extern __shared__ char smem[];
  float*    cjl    = (float*)(smem + 65536);           // 1024 f32
  unsigned* keys_l = (unsigned*)(smem + 69632);        // 256 u32
  float*    xn_l   = (float*)(smem + 70656);           // 256 f32
  float*    red    = (float*)(smem + 71680);           // 16 f32

  int n0 = blockIdx.x * 256;
  int b  = n0 >> 12, hw0 = n0 & 4095;
  int t = threadIdx.x, w = t >> 6, lane = t & 63;
  int quad = lane >> 4, lr = lane & 15;
  int g  = w >> 1;       // n-group 0..7 (32 n)
  int h2 = w & 1;        // k-half (32 k of each 64k tile)

  if (t < 256) { keys_l[t] = 0u; xn_l[t] = 0.f; }
  for (int i = t; i < 1024; i += 1024) cjl[i] = 0.375f - 0.5f * enorm[i];
  __syncthreads();

  // ---- prologue: x[c][hw] -> A-tile bf16, 2 passes of 128 n; float4 reads ----
  bf16x8 af[2][8];
#pragma unroll
  for (int p = 0; p < 2; ++p) {
    if (p) __syncthreads();            // pass-0 af reads done before rewrite
    {
      int hwq = t & 31;                // 4-hw quad -> n-local = hwq*4..+3
      int cg  = t >> 5;                // c-group 0..31 (8 c each)
      const float* xp = x + (size_t)b * (EMB_C * HWB) + hw0 + p * 128 + hwq * 4;
      float xn[4] = {0.f, 0.f, 0.f, 0.f};
      unsigned pk[4][4] = {};
#pragma unroll
      for (int j = 0; j < 8; ++j) {    // c = cg*8 + j
        f32x4 v = *(const f32x4*)(xp + (size_t)(cg * 8 + j) * HWB);  // 16B/lane
#pragma unroll
        for (int m = 0; m < 4; ++m) {
          xn[m] += v[m] * v[m];
          pk[m][j >> 1] |= (unsigned)bf16bits(v[m]) << ((j & 1) * 16);
        }
      }
#pragma unroll
      for (int m = 0; m < 4; ++m) {
        int nl = hwq * 4 + m;
        int pos = ((cg >> 3) << 3) | ((cg & 7) ^ (nl & 7));
        *(uint4*)(smem + nl * 512 + pos * 16) = *(const uint4*)pk[m];
        atomicAdd(&xn_l[p * 128 + nl], xn[m]);
      }
    }
    __syncthreads();
    if ((g >> 2) == p) {               // waves of this pass load af
#pragma unroll
      for (int i = 0; i < 2; ++i) {
        int rA = (g & 3) * 32 + i * 16 + lr;
#pragma unroll
        for (int s = 0; s < 8; ++s) {
          int cc = s * 4 + quad;
          int pos = ((cc >> 3) << 3) | ((cc & 7) ^ (rA & 7));
          af[i][s] = *(const bf16x8*)(smem + rA * 512 + pos * 16);
        }
      }
    }
  }
  __syncthreads();   // af complete; [0,64K) becomes B double buffer

  stage64b(embbf, (unsigned char*)smem, t);   // B(0) into ping
  __syncthreads();

  // ---- K-loop: 16 tiles of 64 k, proven 2-barrier double-buffer ----
  unsigned best[2][4] = {};
  int posB = 0;  // XOR swizzle pos base for this lane (rB&7 == lr&7 for both j)
  for (int kt = 0; kt < 16; ++kt) {
    unsigned char* srcB = (unsigned char*)smem + ((kt & 1) << 15);
    unsigned char* dstB = (unsigned char*)smem + (((kt + 1) & 1) << 15);
    if (kt < 15) stage64b(embbf + (size_t)(kt + 1) * 64 * EMB_C, dstB, t);
    float cj[2]; unsigned kp[2];
#pragma unroll
    for (int j = 0; j < 2; ++j) {
      int k = kt * 64 + h2 * 32 + j * 16 + lr;
      cj[j] = cjl[k];
      kp[j] = 1023u - (unsigned)k;
    }
    f32x4 acc[2][2] = {};
#pragma unroll
    for (int s = 0; s < 8; ++s) {
      int cc = s * 4 + quad;
      int pos = ((cc >> 3) << 3) | ((cc & 7) ^ (lr & 7));
      bf16x8 bf[2];
#pragma unroll
      for (int j = 0; j < 2; ++j)
        bf[j] = *(const bf16x8*)(srcB + (h2 * 32 + j * 16 + lr) * 512 + pos * 16);
#pragma unroll
      for (int i = 0; i < 2; ++i)
#pragma unroll
        for (int j = 0; j < 2; ++j)
          acc[i][j] = __builtin_amdgcn_mfma_f32_16x16x32_bf16(af[i][s], bf[j], acc[i][j], 0, 0, 0);
    }
    (void)posB;
    // fold argmin keys: f = dot + 0.375 - 0.5||e||^2 in (0.04,0.71) -> positive
    // float u32-order-correct; low 10 mantissa bits carry (1023-k).
#pragma unroll
    for (int i = 0; i < 2; ++i)
#pragma unroll
      for (int j = 0; j < 2; ++j)
#pragma unroll
        for (int r = 0; r < 4; ++r) {
          float f = acc[i][j][r] + cj[j];
          unsigned key = (__float_as_uint(f) & 0xFFFFFC00u) | kp[j];
          best[i][r] = best[i][r] > key ? best[i][r] : key;
        }
    __syncthreads();   // srcB reads done before it becomes next dst; dst visible
  }

  // ---- combine keys across k-lanes; k-halves via LDS atomicMax ----
#pragma unroll
  for (int i = 0; i < 2; ++i)
#pragma unroll
    for (int r = 0; r < 4; ++r) {
      unsigned v = best[i][r];
#pragma unroll
      for (int m = 1; m < 16; m <<= 1) {
        unsigned o = (unsigned)__shfl_xor((int)v, m, 64);
        v = v > o ? v : o;
      }
      if (lr == 0) atomicMax(&keys_l[g * 32 + i * 16 + quad * 4 + r], v);
    }
  __syncthreads();

  // ---- loss partial: d2 = ||x||^2 + 0.75 - 2*f_hat ----
  if (t < 256) {
    unsigned key = keys_l[t];
    float fh = __uint_as_float(key & 0xFFFFFC00u);
    float lsum = xn_l[t] + 0.75f - 2.0f * fh;
    for (int m = 32; m; m >>= 1) lsum += __shfl_down(lsum, m, 64);
    if (lane == 0) red[w] = lsum;
  }
  __syncthreads();
  if (t == 0) {
    atomicAdd(loss, red[0] + red[1] + red[2] + red[3]);
    __threadfence();
  }

  // ---- output: gather emb -> LDS [64c][256n] ROTATED by 3 -> aligned f32x4 ----
  // tile[c][(n-3)&255] = emb[idx[n]][c]  =>  ds_read_b128 at 4L reads n=4L+3..
  // and the global f32x4 store at F+3+4L is 16B-aligned despite out+1.
  float* tile = (float*)smem;
  int nn = t >> 2, ch = t & 3;               // 4 threads per n
  int idx = 1023 - (int)(keys_l[nn] & 1023u);
  const float* er = emb + (size_t)idx * EMB_C;
  int nrot = (nn - 3) & 255;
  float* ob = out + 1 + (size_t)b * (EMB_C * HWB) + hw0;
  for (int p = 0; p < 4; ++p) {
    int c0 = p * 64;
    if (p) __syncthreads();
#pragma unroll
    for (int q = 0; q < 4; ++q) {            // 4 x 16B L2-resident gathers
      f32x4 v = *(const f32x4*)(er + c0 + ch * 16 + q * 4);
#pragma unroll
      for (int m = 0; m < 4; ++m)
        tile[(ch * 16 + q * 4 + m) * 256 + nrot] = v[m];
    }
    __syncthreads();
#pragma unroll
    for (int cc = 0; cc < 4; ++cc) {         // wave w: c-rows w*4..w*4+3
      int cl = w * 4 + cc;
      const float* tr = tile + cl * 256;
      float* F = ob + (size_t)(c0 + cl) * HWB;
      if (lane < 63) {
        f32x4 q = *(const f32x4*)(tr + 4 * lane);    // aligned b128
        *(f32x4*)(F + 3 + 4 * lane) = q;             // aligned 16B store
      }
      if (lane == 0) { F[0] = tr[253]; F[1] = tr[254]; F[2] = tr[255]; }
      if (lane == 63) { F[255] = tr[252]; }
    }
  }

  // ---- fused finalize: last block writes out[0] ----
  if (t == 0) {
    unsigned done = atomicAdd(ctr, 1u);
    if (done == gridDim.x - 1) {
      float total = atomicAdd(loss, 0.f);   // device-scope read of final sum
      out[0] = 1.0625f * total / 16777216.0f;
    }
  }
}

extern "C" void kernel_launch(void* const* d_in, const int* in_sizes, int n_in,
                              void* d_out, int out_size, void* d_ws, size_t ws_size,
                              hipStream_t stream) {
  const float* x   = (const float*)d_in[0];   // [16,256,64,64]
  const float* emb = (const float*)d_in[1];   // [1024,256]
  float* out = (float*)d_out;                 // [1 + 16777216]
  char*  ws  = (char*)d_ws;

  unsigned short* emb_bf = (unsigned short*)ws;                 // 512 KB
  float*          enorm  = (float*)(ws + 524288);               // 4 KB
  float*          loss   = (float*)(ws + 528384);               // 4 B
  unsigned*       ctr    = (unsigned*)(ws + 528388);            // 4 B

  hipFuncSetAttribute((const void*)k_main,
                      hipFuncAttributeMaxDynamicSharedMemorySize, LDS_BYTES);

  k_emb <<<dim3(EMB_K),      dim3(EMB_C), 0,         stream>>>(emb, emb_bf, enorm, loss, ctr);
  k_main<<<dim3(NPIX / 256), dim3(1024),  LDS_BYTES, stream>>>(x, emb, emb_bf, enorm,
                                                               out, loss, ctr);
}